// Round 5
// baseline (510.178 us; speedup 1.0000x reference)
//
#include <hip/hip_runtime.h>
#include <hip/hip_bf16.h>

typedef __attribute__((ext_vector_type(8))) short short8;
typedef __attribute__((ext_vector_type(4))) float f32x4;
typedef __attribute__((ext_vector_type(4))) unsigned u32x4;

// LDS layout (bytes) — 40960 total => 4 blocks/CU (160 KiB LDS):
//   hres [48][104] bf16 @ 0      (9984)
//   buf1 [48][104] bf16 @ 9984   (9984)   o (attn out)
//   buf2 q[32][104]|k[32][104]|vT[96][40] @ 19968 (20992) -> f1[48][200]
#define LDS_BYTES 40960
#define SH   104
#define SU   52
#define KOFF 3328
#define VOFF 6656
#define F1S  200
#define F1SU 100

#if __has_builtin(__builtin_amdgcn_cvt_pk_bf16_f32)
typedef __attribute__((ext_vector_type(2))) __bf16 bf16x2;
__device__ __forceinline__ unsigned pk2bf(float a, float b){
  bf16x2 v = __builtin_amdgcn_cvt_pk_bf16_f32(a, b);
  return __builtin_bit_cast(unsigned, v);
}
__device__ __forceinline__ unsigned short f2bf(float x){
  bf16x2 v = __builtin_amdgcn_cvt_pk_bf16_f32(x, x);
  return (unsigned short)(__builtin_bit_cast(unsigned, v) & 0xFFFFu);
}
#else
__device__ __forceinline__ unsigned short f2bf(float x){
  unsigned u = __float_as_uint(x);
  u += 0x7FFFu + ((u >> 16) & 1u);
  return (unsigned short)(u >> 16);
}
__device__ __forceinline__ unsigned pk2bf(float a, float b){
  return (unsigned)f2bf(a) | ((unsigned)f2bf(b) << 16);
}
#endif

#if __has_builtin(__builtin_amdgcn_rcpf)
__device__ __forceinline__ float fast_rcp(float x){ return __builtin_amdgcn_rcpf(x); }
#else
__device__ __forceinline__ float fast_rcp(float x){ return 1.f/x; }
#endif
#if __has_builtin(__builtin_amdgcn_rsqf)
__device__ __forceinline__ float fast_rsq(float x){ return __builtin_amdgcn_rsqf(x); }
#else
__device__ __forceinline__ float fast_rsq(float x){ return rsqrtf(x); }
#endif
#if __has_builtin(__builtin_amdgcn_exp2f)
__device__ __forceinline__ float fast_ex2(float x){ return __builtin_amdgcn_exp2f(x); }
#else
__device__ __forceinline__ float fast_ex2(float x){ return exp2f(x); }
#endif

__device__ __forceinline__ float bflo(unsigned u){ return __uint_as_float(u << 16); }
__device__ __forceinline__ float bfhi(unsigned u){ return __uint_as_float(u & 0xFFFF0000u); }
__device__ __forceinline__ float bf1(unsigned short h){ return __uint_as_float(((unsigned)h) << 16); }

// ---------------- zero only the atomic-target stripes of out ----------------
__global__ void zero_stripes(float* __restrict__ out){
  int k = blockIdx.x;          // 0..341
  int b = blockIdx.y;          // 0..31
  int t = threadIdx.x;         // 0..191 : 8 tokens x 24 float4
  int tok = 24*k + (t / 24);
  f32x4 z = {0.f, 0.f, 0.f, 0.f};
  *(f32x4*)(out + ((size_t)b*8192 + tok)*96 + 4*(t % 24)) = z;
}

// ---------------- weight pre-pack: fp32 [K][N] -> bf16 MFMA fragments ----------------
__global__ void pack_weights(const float* __restrict__ qkv_w, const float* __restrict__ out_w,
                             const float* __restrict__ ffn_w1, const float* __restrict__ ffn_w2,
                             short8* __restrict__ wsv){
  int f = blockIdx.x, lane = threadIdx.x;
  const float* W; int N, nt, kf;
  if (f < 54)      { W = qkv_w;  N = 288; nt = f/3;        kf = f%3; }
  else if (f < 72) { int i=f-54;  W = out_w;  N = 96;  nt = i/3; kf = i%3; }
  else if (f < 108){ int i=f-72;  W = ffn_w1; N = 192; nt = i/3; kf = i%3; }
  else             { int i=f-108; W = ffn_w2; N = 96;  nt = i/6; kf = i%6; }
  int n = lane & 15, kq = lane >> 4;
  short8 v;
#pragma unroll
  for (int j = 0; j < 8; ++j){
    int k = kf*32 + kq*8 + j;
    v[j] = (short)f2bf(W[(size_t)k * N + nt*16 + n]);
  }
  wsv[f*64 + lane] = v;
}

// ---------------- fused block kernel ----------------
// 512 thr (8 waves). Phase-count surgery: LN1 fused into QKV (h in registers, never in
// LDS), LN2 fused into FFN1 (in-register from packed hres u32). 5 barriers (was 7).
// No mass operand hoisting (R4 spilled: WRITE_SIZE 131->205MB); per-tile reads kept.
__global__ __launch_bounds__(512, 8)
void fused_block(const float* __restrict__ x,
                 const float* __restrict__ ln1_g, const float* __restrict__ ln1_b,
                 const float* __restrict__ qkv_b,
                 const float* __restrict__ out_b,
                 const float* __restrict__ ln2_g, const float* __restrict__ ln2_b,
                 const float* __restrict__ ffn_b1, const float* __restrict__ ffn_b2,
                 const float* __restrict__ pln_g, const float* __restrict__ pln_b,
                 const short8* __restrict__ wsv,
                 float* __restrict__ out)
{
  __shared__ __align__(16) char smem[LDS_BYTES];
  unsigned short* hres  = (unsigned short*)smem;
  unsigned*       hresU = (unsigned*)smem;
  unsigned short* buf1  = (unsigned short*)(smem + 9984);
  unsigned*       buf1U = (unsigned*)(smem + 9984);
  unsigned short* buf2  = (unsigned short*)(smem + 19968);
  unsigned*       buf2U = (unsigned*)(smem + 19968);

  const int tid  = threadIdx.x;
  const int wave = tid >> 6, lane = tid & 63;
  const int lm   = lane & 15, quad = lane >> 4;
  __builtin_assume(wave >= 0 && wave < 8);
  __builtin_assume(lm >= 0 && lm < 16);
  __builtin_assume(quad >= 0 && quad < 4);
  const int g = blockIdx.x, b = blockIdx.y;
  const int t0 = 24 * g;
  const size_t xbase = ((size_t)b * 8192 + t0) * 96;
  const short8* wl = wsv + lane;

  // ---------- Phase 1: fused LN1 + QKV (h entirely in registers; no barrier before)
  {
    const int mt = wave & 1, p = wave >> 1;
    __builtin_assume(p >= 0 && p < 4);
    const int row = 16*mt + lm;
    const float* xr = x + xbase + (size_t)row*96 + quad*8;
    float v0[8], v1[8], v2[8];
    {
      f32x4 a = *(const f32x4*)(xr);       f32x4 c = *(const f32x4*)(xr + 4);
#pragma unroll
      for (int j = 0; j < 4; ++j){ v0[j] = a[j]; v0[4+j] = c[j]; }
    }
    {
      f32x4 a = *(const f32x4*)(xr + 32);  f32x4 c = *(const f32x4*)(xr + 36);
#pragma unroll
      for (int j = 0; j < 4; ++j){ v1[j] = a[j]; v1[4+j] = c[j]; }
    }
    {
      f32x4 a = *(const f32x4*)(xr + 64);  f32x4 c = *(const f32x4*)(xr + 68);
#pragma unroll
      for (int j = 0; j < 4; ++j){ v2[j] = a[j]; v2[4+j] = c[j]; }
    }
    float s = 0.f, q2 = 0.f;
#pragma unroll
    for (int j = 0; j < 8; ++j){
      s += v0[j] + v1[j] + v2[j];
      q2 += v0[j]*v0[j] + v1[j]*v1[j] + v2[j]*v2[j];
    }
    s  += __shfl_xor(s, 16);  q2 += __shfl_xor(q2, 16);
    s  += __shfl_xor(s, 32);  q2 += __shfl_xor(q2, 32);
    float mean = s * (1.f/96.f);
    float rstd = fast_rsq(q2 * (1.f/96.f) - mean*mean + 1e-5f);

    short8 h0, h1, h2;
    auto mkfrag = [&](const float* vv, int kf)->short8{
      const float* gp = ln1_g + kf*32 + quad*8;
      const float* bp = ln1_b + kf*32 + quad*8;
      f32x4 ga = *(const f32x4*)(gp), gb = *(const f32x4*)(gp + 4);
      f32x4 ba = *(const f32x4*)(bp), bb = *(const f32x4*)(bp + 4);
      u32x4 hu;
      hu[0] = pk2bf((vv[0]-mean)*rstd*ga[0]+ba[0], (vv[1]-mean)*rstd*ga[1]+ba[1]);
      hu[1] = pk2bf((vv[2]-mean)*rstd*ga[2]+ba[2], (vv[3]-mean)*rstd*ga[3]+ba[3]);
      hu[2] = pk2bf((vv[4]-mean)*rstd*gb[0]+bb[0], (vv[5]-mean)*rstd*gb[1]+bb[1]);
      hu[3] = pk2bf((vv[6]-mean)*rstd*gb[2]+bb[2], (vv[7]-mean)*rstd*gb[3]+bb[3]);
      return __builtin_bit_cast(short8, hu);
    };
    h0 = mkfrag(v0, 0); h1 = mkfrag(v1, 1); h2 = mkfrag(v2, 2);

    auto qkv_tile = [&](int nt){
      if (nt < 12){
        f32x4 acc0 = *(const f32x4*)(qkv_b + nt*16 + quad*4);
        f32x4 acc1 = {0.f,0.f,0.f,0.f};
        acc0 = __builtin_amdgcn_mfma_f32_16x16x32_bf16(wl[(nt*3+0)*64], h0, acc0, 0, 0, 0);
        acc1 = __builtin_amdgcn_mfma_f32_16x16x32_bf16(wl[(nt*3+1)*64], h1, acc1, 0, 0, 0);
        acc0 = __builtin_amdgcn_mfma_f32_16x16x32_bf16(wl[(nt*3+2)*64], h2, acc0, 0, 0, 0);
        unsigned idx = (nt < 6)
          ? (unsigned)(row*SU + nt*8 + quad*2)
          : (unsigned)((KOFF>>1) + row*SU + (nt-6)*8 + quad*2);
        buf2U[idx]     = pk2bf(acc0[0]+acc1[0], acc0[1]+acc1[1]);
        buf2U[idx + 1] = pk2bf(acc0[2]+acc1[2], acc0[3]+acc1[3]);
      } else {
        int col = nt*16 + lm;
        float bias = qkv_b[col];
        f32x4 acc0 = {bias, bias, bias, bias};
        f32x4 acc1 = {0.f,0.f,0.f,0.f};
        acc0 = __builtin_amdgcn_mfma_f32_16x16x32_bf16(h0, wl[(nt*3+0)*64], acc0, 0, 0, 0);
        acc1 = __builtin_amdgcn_mfma_f32_16x16x32_bf16(h1, wl[(nt*3+1)*64], acc1, 0, 0, 0);
        acc0 = __builtin_amdgcn_mfma_f32_16x16x32_bf16(h2, wl[(nt*3+2)*64], acc0, 0, 0, 0);
        int d2 = col - 192;
        int w0 = (VOFF >> 1) + d2*20 + 8*mt + 2*quad;
        buf2U[w0]     = pk2bf(acc0[0]+acc1[0], acc0[1]+acc1[1]);
        buf2U[w0 + 1] = pk2bf(acc0[2]+acc1[2], acc0[3]+acc1[3]);
      }
    };
#pragma unroll
    for (int i = 0; i < 4; ++i) qkv_tile(p + 4*i);
    if (p < 2) qkv_tile(p + 16);
  }
  __syncthreads();   // barrier 1

  // ---------- Phase 2: attention, 18 units (3 windows x 6 heads); per-unit reads
  {
    auto attn_unit = [&](int u){
      int w = u / 6, h = u - 6*(u / 6);
      short8 qa = {0,0,0,0,0,0,0,0}, ka = {0,0,0,0,0,0,0,0};
      if (quad < 2){
        qa = *(const short8*)(buf2 +        (8*w + lm)*SH + h*16 + quad*8);
        ka = *(const short8*)(buf2 + KOFF + (8*w + lm)*SH + h*16 + quad*8);
      }
      f32x4 sc = {0.f,0.f,0.f,0.f};
      sc = __builtin_amdgcn_mfma_f32_16x16x32_bf16(ka, qa, sc, 0, 0, 0);
      float p4[4]; float sum = 0.f;
#pragma unroll
      for (int r = 0; r < 4; ++r){
        int k = quad*4 + r;
        float e = fast_ex2(sc[r]*0.36067376f);   // exp(s*0.25) = exp2(s*0.25*log2e)
        p4[r] = (k <= lm) ? e : 0.f;
        sum += p4[r];
      }
      sum += __shfl_xor(sum, 16);
      sum += __shfl_xor(sum, 32);
      float rs = fast_rcp(sum);
      int x0 = (int)pk2bf(p4[0]*rs, p4[1]*rs);
      int x1 = (int)pk2bf(p4[2]*rs, p4[3]*rs);
      int srcA = lm + ((quad & 1) << 5);
      int e0 = __shfl(x0, srcA),      e1 = __shfl(x1, srcA);
      int e2 = __shfl(x0, srcA + 16), e3 = __shfl(x1, srcA + 16);
      short8 pa = {0,0,0,0,0,0,0,0}, va = {0,0,0,0,0,0,0,0};
      if (quad < 2){
        u32x4 t = {(unsigned)e0, (unsigned)e1, (unsigned)e2, (unsigned)e3};
        pa = __builtin_bit_cast(short8, t);
        va = *(const short8*)(buf2 + VOFF + (h*16 + lm)*40 + 8*w + quad*8);
      }
      f32x4 oc = {0.f,0.f,0.f,0.f};
      oc = __builtin_amdgcn_mfma_f32_16x16x32_bf16(va, pa, oc, 0, 0, 0); // O^T[d][q]
      unsigned ob = (w*16 + lm)*SU + h*8 + quad*2;
      buf1U[ob]     = pk2bf(oc[0], oc[1]);
      buf1U[ob + 1] = pk2bf(oc[2], oc[3]);
    };
    attn_unit(wave);
    attn_unit(wave + 8);
    if (wave < 2) attn_unit(wave + 16);
  }
  __syncthreads();   // barrier 2

  // ---------- Phase 3: out-proj + residual, 18 tiles round-robin -> hres
  {
    auto oproj_tile = [&](int tile){
      int w = tile / 6, nt = tile - 6*(tile / 6);
      f32x4 acc0 = *(const f32x4*)(out_b + nt*16 + quad*4);
      f32x4 acc1 = {0.f,0.f,0.f,0.f};
      const unsigned short* arow = buf1 + (w*16 + lm)*SH + quad*8;
      short8 a0 = *(const short8*)(arow);
      short8 a1 = *(const short8*)(arow + 32);
      short8 a2 = *(const short8*)(arow + 64);
      acc0 = __builtin_amdgcn_mfma_f32_16x16x32_bf16(wl[(54 + nt*3 + 0)*64], a0, acc0, 0, 0, 0);
      acc1 = __builtin_amdgcn_mfma_f32_16x16x32_bf16(wl[(54 + nt*3 + 1)*64], a1, acc1, 0, 0, 0);
      acc0 = __builtin_amdgcn_mfma_f32_16x16x32_bf16(wl[(54 + nt*3 + 2)*64], a2, acc0, 0, 0, 0);
      f32x4 xr = *(const f32x4*)(x + xbase + (size_t)(8*w + lm)*96 + nt*16 + quad*4);
      unsigned idx = (w*16 + lm)*SU + nt*8 + quad*2;
      hresU[idx]     = pk2bf(acc0[0]+acc1[0]+xr[0], acc0[1]+acc1[1]+xr[1]);
      hresU[idx + 1] = pk2bf(acc0[2]+acc1[2]+xr[2], acc0[3]+acc1[3]+xr[3]);
    };
    oproj_tile(wave);
    oproj_tile(wave + 8);
    if (wave < 2) oproj_tile(wave + 16);
  }
  __syncthreads();   // barrier 3

  // ---------- Phase 4: fused LN2 + FFN1 + gelu; waves 0-5 own (mt, 6 nt) -> f1 (buf2)
  if (wave < 6){
    const int mt = wave >> 1, ntb = (wave & 1)*6;
    const int row = 16*mt + lm;
    const unsigned short* hr = hres + row*SH + quad*8;
    short8 r0 = *(const short8*)(hr);
    short8 r1 = *(const short8*)(hr + 32);
    short8 r2 = *(const short8*)(hr + 64);
    u32x4 c0 = __builtin_bit_cast(u32x4, r0);
    u32x4 c1 = __builtin_bit_cast(u32x4, r1);
    u32x4 c2 = __builtin_bit_cast(u32x4, r2);
    float s = 0.f, q2 = 0.f;
#pragma unroll
    for (int t = 0; t < 4; ++t){
      float a0 = bflo(c0[t]), a1 = bfhi(c0[t]);
      float a2 = bflo(c1[t]), a3 = bfhi(c1[t]);
      float a4 = bflo(c2[t]), a5 = bfhi(c2[t]);
      s  += a0+a1+a2+a3+a4+a5;
      q2 += a0*a0+a1*a1+a2*a2+a3*a3+a4*a4+a5*a5;
    }
    s  += __shfl_xor(s, 16);  q2 += __shfl_xor(q2, 16);
    s  += __shfl_xor(s, 32);  q2 += __shfl_xor(q2, 32);
    float mean = s * (1.f/96.f);
    float rstd = fast_rsq(q2 * (1.f/96.f) - mean*mean + 1e-5f);

    short8 a0f, a1f, a2f;
    auto mkfrag2 = [&](u32x4 c, int kf)->short8{
      const float* gp = ln2_g + kf*32 + quad*8;
      const float* bp = ln2_b + kf*32 + quad*8;
      f32x4 ga = *(const f32x4*)(gp), gb = *(const f32x4*)(gp + 4);
      f32x4 ba = *(const f32x4*)(bp), bb = *(const f32x4*)(bp + 4);
      u32x4 hu;
      hu[0] = pk2bf((bflo(c[0])-mean)*rstd*ga[0]+ba[0], (bfhi(c[0])-mean)*rstd*ga[1]+ba[1]);
      hu[1] = pk2bf((bflo(c[1])-mean)*rstd*ga[2]+ba[2], (bfhi(c[1])-mean)*rstd*ga[3]+ba[3]);
      hu[2] = pk2bf((bflo(c[2])-mean)*rstd*gb[0]+bb[0], (bfhi(c[2])-mean)*rstd*gb[1]+bb[1]);
      hu[3] = pk2bf((bflo(c[3])-mean)*rstd*gb[2]+bb[2], (bfhi(c[3])-mean)*rstd*gb[3]+bb[3]);
      return __builtin_bit_cast(short8, hu);
    };
    a0f = mkfrag2(c0, 0); a1f = mkfrag2(c1, 1); a2f = mkfrag2(c2, 2);

#pragma unroll
    for (int i = 0; i < 6; ++i){
      int nt = ntb + i;
      f32x4 acc0 = *(const f32x4*)(ffn_b1 + nt*16 + quad*4);
      f32x4 acc1 = {0.f,0.f,0.f,0.f};
      acc0 = __builtin_amdgcn_mfma_f32_16x16x32_bf16(wl[(72 + nt*3 + 0)*64], a0f, acc0, 0, 0, 0);
      acc1 = __builtin_amdgcn_mfma_f32_16x16x32_bf16(wl[(72 + nt*3 + 1)*64], a1f, acc1, 0, 0, 0);
      acc0 = __builtin_amdgcn_mfma_f32_16x16x32_bf16(wl[(72 + nt*3 + 2)*64], a2f, acc0, 0, 0, 0);
      float gl[4];
#pragma unroll
      for (int r = 0; r < 4; ++r){
        float uu = acc0[r] + acc1[r];
        float z = -2.3022081f * (uu + 0.044715f * uu*uu*uu);   // -(2z)*log2e
        float e = fast_ex2(z);
        gl[r] = uu * fast_rcp(1.f + e);          // u * sigmoid(2z)
      }
      unsigned idx = (mt*16 + lm)*F1SU + nt*8 + quad*2;
      buf2U[idx]     = pk2bf(gl[0], gl[1]);
      buf2U[idx + 1] = pk2bf(gl[2], gl[3]);
    }
  }
  __syncthreads();   // barrier 4

  // ---------- Phase 5: FFN2 + residual, 18 tiles round-robin, K=192 -> hres RMW
  {
    auto ffn2_tile = [&](int tile){
      int mt = tile / 6, nt = tile - 6*(tile / 6);
      const unsigned short* frow = buf2 + (mt*16 + lm)*F1S + quad*8;
      short8 f0 = *(const short8*)(frow);
      short8 f1 = *(const short8*)(frow + 32);
      short8 f2 = *(const short8*)(frow + 64);
      short8 f3 = *(const short8*)(frow + 96);
      short8 f4 = *(const short8*)(frow + 128);
      short8 f5 = *(const short8*)(frow + 160);
      f32x4 acc0 = *(const f32x4*)(ffn_b2 + nt*16 + quad*4);
      f32x4 acc1 = {0.f,0.f,0.f,0.f};
      acc0 = __builtin_amdgcn_mfma_f32_16x16x32_bf16(wl[(108 + nt*6 + 0)*64], f0, acc0, 0, 0, 0);
      acc1 = __builtin_amdgcn_mfma_f32_16x16x32_bf16(wl[(108 + nt*6 + 1)*64], f1, acc1, 0, 0, 0);
      acc0 = __builtin_amdgcn_mfma_f32_16x16x32_bf16(wl[(108 + nt*6 + 2)*64], f2, acc0, 0, 0, 0);
      acc1 = __builtin_amdgcn_mfma_f32_16x16x32_bf16(wl[(108 + nt*6 + 3)*64], f3, acc1, 0, 0, 0);
      acc0 = __builtin_amdgcn_mfma_f32_16x16x32_bf16(wl[(108 + nt*6 + 4)*64], f4, acc0, 0, 0, 0);
      acc1 = __builtin_amdgcn_mfma_f32_16x16x32_bf16(wl[(108 + nt*6 + 5)*64], f5, acc1, 0, 0, 0);
      unsigned idx = (mt*16 + lm)*SU + nt*8 + quad*2;
      unsigned u0 = hresU[idx], u1 = hresU[idx + 1];
      hresU[idx]     = pk2bf(bflo(u0)+acc0[0]+acc1[0], bfhi(u0)+acc0[1]+acc1[1]);
      hresU[idx + 1] = pk2bf(bflo(u1)+acc0[2]+acc1[2], bfhi(u1)+acc0[3]+acc1[3]);
    };
    ffn2_tile(wave);
    ffn2_tile(wave + 8);
    if (wave < 2) ffn2_tile(wave + 16);
  }
  __syncthreads();   // barrier 5

  // ---------- Phase 6: merged post-LN + combine + store
  {
    const int i = tid >> 4, c0 = tid & 15;
    const int l = t0 + i;
    const size_t obase = ((size_t)b * 8192 + l) * 96;
    int rowA, rowB = -1;
    if (i < 8)       rowA = i;
    else if (i < 16){ rowA = i;            rowB = 16 + (i - 8); }
    else if (i < 24){ rowA = 16 + (i - 8); rowB = 32 + (i - 16); }
    else             rowA = 32 + (i - 16);

    float g6[6], b6[6];
#pragma unroll
    for (int e = 0; e < 6; ++e){ g6[e] = pln_g[c0 + 16*e]; b6[e] = pln_b[c0 + 16*e]; }

    float yA[6];
    {
      float v[6];
#pragma unroll
      for (int e = 0; e < 6; ++e) v[e] = bf1(hres[rowA*SH + c0 + 16*e]);
      float s = 0.f, q2 = 0.f;
#pragma unroll
      for (int e = 0; e < 6; ++e){ s += v[e]; q2 += v[e]*v[e]; }
#pragma unroll
      for (int m = 1; m < 16; m <<= 1){ s += __shfl_xor(s, m, 16); q2 += __shfl_xor(q2, m, 16); }
      float mean = s * (1.f/96.f);
      float rstd = fast_rsq(q2 * (1.f/96.f) - mean*mean + 1e-5f);
#pragma unroll
      for (int e = 0; e < 6; ++e) yA[e] = (v[e]-mean)*rstd*g6[e] + b6[e];
    }
    if (rowB >= 0){
      float yB[6];
      {
        float v[6];
#pragma unroll
        for (int e = 0; e < 6; ++e) v[e] = bf1(hres[rowB*SH + c0 + 16*e]);
        float s = 0.f, q2 = 0.f;
#pragma unroll
        for (int e = 0; e < 6; ++e){ s += v[e]; q2 += v[e]*v[e]; }
#pragma unroll
        for (int m = 1; m < 16; m <<= 1){ s += __shfl_xor(s, m, 16); q2 += __shfl_xor(q2, m, 16); }
        float mean = s * (1.f/96.f);
        float rstd = fast_rsq(q2 * (1.f/96.f) - mean*mean + 1e-5f);
#pragma unroll
        for (int e = 0; e < 6; ++e) yB[e] = (v[e]-mean)*rstd*g6[e] + b6[e];
      }
#pragma unroll
      for (int e = 0; e < 6; ++e)
        out[obase + c0 + 16*e] = 0.5f * (yA[e] + yB[e]);
    } else {
      float inv = (l < 8 || l >= 8184) ? 1.0f : 0.5f;
#pragma unroll
      for (int e = 0; e < 6; ++e)
        atomicAdd(&out[obase + c0 + 16*e], yA[e] * inv);
    }
  }
}

extern "C" void kernel_launch(void* const* d_in, const int* in_sizes, int n_in,
                              void* d_out, int out_size, void* d_ws, size_t ws_size,
                              hipStream_t stream) {
  const float* x      = (const float*)d_in[0];
  const float* ln1_g  = (const float*)d_in[1];
  const float* ln1_b  = (const float*)d_in[2];
  const float* qkv_w  = (const float*)d_in[3];
  const float* qkv_b  = (const float*)d_in[4];
  const float* out_w  = (const float*)d_in[5];
  const float* out_b  = (const float*)d_in[6];
  const float* ln2_g  = (const float*)d_in[7];
  const float* ln2_b  = (const float*)d_in[8];
  const float* ffn_w1 = (const float*)d_in[9];
  const float* ffn_b1 = (const float*)d_in[10];
  const float* ffn_w2 = (const float*)d_in[11];
  const float* ffn_b2 = (const float*)d_in[12];
  const float* pln_g  = (const float*)d_in[13];
  const float* pln_b  = (const float*)d_in[14];
  float* out = (float*)d_out;
  short8* wsv = (short8*)d_ws;

  zero_stripes<<<dim3(342, 32), 192, 0, stream>>>(out);
  pack_weights<<<144, 64, 0, stream>>>(qkv_w, out_w, ffn_w1, ffn_w2, wsv);
  fused_block<<<dim3(341, 32), 512, 0, stream>>>(
      x, ln1_g, ln1_b, qkv_b, out_b, ln2_g, ln2_b, ffn_b1, ffn_b2,
      pln_g, pln_b, (const short8*)wsv, out);
}

// Round 6
// 469.802 us; speedup vs baseline: 1.0859x; 1.0859x over previous
//
#include <hip/hip_runtime.h>
#include <hip/hip_bf16.h>

typedef __attribute__((ext_vector_type(8))) short short8;
typedef __attribute__((ext_vector_type(4))) float f32x4;
typedef __attribute__((ext_vector_type(4))) unsigned u32x4;

// LDS layout (bytes), lifetime-overlaid — 40960 total => 4 blocks/CU:
//   region A [0,20992):      ph1-2: q[32][104] | k@KOFF | vT[96][40]
//                            ph3+:  hres[56][104] @ 0 (11648) ; f1prefix[8][200] @ 11648
//   region B [20992,32640):  ph0: hln[32][104] ; ph2-3: o[56][104]
//   f1main  [20992,40192):   ph4+: f1[48][200] (overlays dead o)
#define LDS_BYTES 40960
#define SH   104
#define SU   52
#define KOFF 3328     // k shorts offset (region A)
#define VOFF 6656     // vT shorts offset
#define OB_S 10496    // hln / o shorts base (byte 20992)
#define OB_U 5248
#define F1M_S 10496   // f1 main shorts base (byte 20992)
#define F1M_U 5248
#define F1P_S 5824    // f1 prefix shorts base (byte 11648)
#define F1P_U 2912
#define F1S  200
#define F1SU 100

#if __has_builtin(__builtin_amdgcn_cvt_pk_bf16_f32)
typedef __attribute__((ext_vector_type(2))) __bf16 bf16x2;
__device__ __forceinline__ unsigned pk2bf(float a, float b){
  bf16x2 v = __builtin_amdgcn_cvt_pk_bf16_f32(a, b);
  return __builtin_bit_cast(unsigned, v);
}
__device__ __forceinline__ unsigned short f2bf(float x){
  bf16x2 v = __builtin_amdgcn_cvt_pk_bf16_f32(x, x);
  return (unsigned short)(__builtin_bit_cast(unsigned, v) & 0xFFFFu);
}
#else
__device__ __forceinline__ unsigned short f2bf(float x){
  unsigned u = __float_as_uint(x);
  u += 0x7FFFu + ((u >> 16) & 1u);
  return (unsigned short)(u >> 16);
}
__device__ __forceinline__ unsigned pk2bf(float a, float b){
  return (unsigned)f2bf(a) | ((unsigned)f2bf(b) << 16);
}
#endif

#if __has_builtin(__builtin_amdgcn_rcpf)
__device__ __forceinline__ float fast_rcp(float x){ return __builtin_amdgcn_rcpf(x); }
#else
__device__ __forceinline__ float fast_rcp(float x){ return 1.f/x; }
#endif
#if __has_builtin(__builtin_amdgcn_rsqf)
__device__ __forceinline__ float fast_rsq(float x){ return __builtin_amdgcn_rsqf(x); }
#else
__device__ __forceinline__ float fast_rsq(float x){ return rsqrtf(x); }
#endif
#if __has_builtin(__builtin_amdgcn_exp2f)
__device__ __forceinline__ float fast_ex2(float x){ return __builtin_amdgcn_exp2f(x); }
#else
__device__ __forceinline__ float fast_ex2(float x){ return exp2f(x); }
#endif

__device__ __forceinline__ float bflo(unsigned u){ return __uint_as_float(u << 16); }
__device__ __forceinline__ float bfhi(unsigned u){ return __uint_as_float(u & 0xFFFF0000u); }
__device__ __forceinline__ float bf1(unsigned short h){ return __uint_as_float(((unsigned)h) << 16); }

// ---------------- weight pre-pack: fp32 [K][N] -> bf16 MFMA fragments ----------------
__global__ void pack_weights(const float* __restrict__ qkv_w, const float* __restrict__ out_w,
                             const float* __restrict__ ffn_w1, const float* __restrict__ ffn_w2,
                             short8* __restrict__ wsv){
  int f = blockIdx.x, lane = threadIdx.x;
  const float* W; int N, nt, kf;
  if (f < 54)      { W = qkv_w;  N = 288; nt = f/3;        kf = f%3; }
  else if (f < 72) { int i=f-54;  W = out_w;  N = 96;  nt = i/3; kf = i%3; }
  else if (f < 108){ int i=f-72;  W = ffn_w1; N = 192; nt = i/3; kf = i%3; }
  else             { int i=f-108; W = ffn_w2; N = 96;  nt = i/6; kf = i%6; }
  int n = lane & 15, kq = lane >> 4;
  short8 v;
#pragma unroll
  for (int j = 0; j < 8; ++j){
    int k = kf*32 + kq*8 + j;
    v[j] = (short)f2bf(W[(size_t)k * N + nt*16 + n]);
  }
  wsv[f*64 + lane] = v;
}

// ---------------- fused block kernel ----------------
// Block g owns output tokens 24g+8..24g+31 exclusively (g=0 also 0..7): the causal
// prefix (rows 0-7) of window 3g+3 only needs tokens 24g+24..31, so it is computed
// redundantly here. NO atomics, NO zero-fill kernel. 24 attn units / 24 oproj tiles /
// 48 ffn1 units / 24 ffn2 tiles -> all phases wave-balanced. LN2 fused into FFN1.
__global__ __launch_bounds__(512, 8)
void fused_block(const float* __restrict__ x,
                 const float* __restrict__ ln1_g, const float* __restrict__ ln1_b,
                 const float* __restrict__ qkv_b,
                 const float* __restrict__ out_b,
                 const float* __restrict__ ln2_g, const float* __restrict__ ln2_b,
                 const float* __restrict__ ffn_b1, const float* __restrict__ ffn_b2,
                 const float* __restrict__ pln_g, const float* __restrict__ pln_b,
                 const short8* __restrict__ wsv,
                 float* __restrict__ out)
{
  __shared__ __align__(16) char smem[LDS_BYTES];
  unsigned short* sS = (unsigned short*)smem;
  unsigned*       sU = (unsigned*)smem;

  const int tid  = threadIdx.x;
  const int wave = tid >> 6, lane = tid & 63;
  const int lm   = lane & 15, quad = lane >> 4;
  __builtin_assume(wave >= 0 && wave < 8);
  __builtin_assume(lm >= 0 && lm < 16);
  __builtin_assume(quad >= 0 && quad < 4);
  const int g = blockIdx.x, b = blockIdx.y;
  const int t0 = 24 * g;
  const size_t xbase = ((size_t)b * 8192 + t0) * 96;
  const short8* wl = wsv + lane;

  // ---------- ph0: LN1 over 32 tokens -> hln bf16 @ region B
  {
    const int row = tid >> 4, j = tid & 15;
    const float* xr = x + xbase + (size_t)row*96 + 6*j;
    float v[6];
#pragma unroll
    for (int e = 0; e < 3; ++e){ float2 t = *(const float2*)(xr + 2*e); v[2*e]=t.x; v[2*e+1]=t.y; }
    float s = 0.f, q2 = 0.f;
#pragma unroll
    for (int e = 0; e < 6; ++e){ s += v[e]; q2 += v[e]*v[e]; }
#pragma unroll
    for (int m = 1; m < 16; m <<= 1){ s += __shfl_xor(s, m, 16); q2 += __shfl_xor(q2, m, 16); }
    float mean = s * (1.f/96.f);
    float rstd = fast_rsq(q2 * (1.f/96.f) - mean*mean + 1e-5f);
#pragma unroll
    for (int e = 0; e < 3; ++e){
      float2 gg = *(const float2*)(ln1_g + 6*j + 2*e);
      float2 bb = *(const float2*)(ln1_b + 6*j + 2*e);
      sU[OB_U + row*SU + 3*j + e] = pk2bf((v[2*e]-mean)*rstd*gg.x+bb.x,
                                          (v[2*e+1]-mean)*rstd*gg.y+bb.y);
    }
  }
  __syncthreads();   // barrier 1

  // ---------- ph1: QKV M=32 N=288 K=96 -> q/k/vT @ region A
  {
    const int mt = wave & 1, p = wave >> 1;
    __builtin_assume(p >= 0 && p < 4);
    const unsigned short* arow = sS + OB_S + (16*mt + lm)*SH + quad*8;
    short8 h0 = *(const short8*)(arow);
    short8 h1 = *(const short8*)(arow + 32);
    short8 h2 = *(const short8*)(arow + 64);
    auto qkv_tile = [&](int nt){
      if (nt < 12){
        f32x4 acc0 = *(const f32x4*)(qkv_b + nt*16 + quad*4);
        f32x4 acc1 = {0.f,0.f,0.f,0.f};
        acc0 = __builtin_amdgcn_mfma_f32_16x16x32_bf16(wl[(nt*3+0)*64], h0, acc0, 0, 0, 0);
        acc1 = __builtin_amdgcn_mfma_f32_16x16x32_bf16(wl[(nt*3+1)*64], h1, acc1, 0, 0, 0);
        acc0 = __builtin_amdgcn_mfma_f32_16x16x32_bf16(wl[(nt*3+2)*64], h2, acc0, 0, 0, 0);
        int row = 16*mt + lm;
        unsigned idx = (nt < 6)
          ? (unsigned)(row*SU + nt*8 + quad*2)
          : (unsigned)((KOFF>>1) + row*SU + (nt-6)*8 + quad*2);
        sU[idx]     = pk2bf(acc0[0]+acc1[0], acc0[1]+acc1[1]);
        sU[idx + 1] = pk2bf(acc0[2]+acc1[2], acc0[3]+acc1[3]);
      } else {
        int col = nt*16 + lm;
        float bias = qkv_b[col];
        f32x4 acc0 = {bias, bias, bias, bias};
        f32x4 acc1 = {0.f,0.f,0.f,0.f};
        acc0 = __builtin_amdgcn_mfma_f32_16x16x32_bf16(h0, wl[(nt*3+0)*64], acc0, 0, 0, 0);
        acc1 = __builtin_amdgcn_mfma_f32_16x16x32_bf16(h1, wl[(nt*3+1)*64], acc1, 0, 0, 0);
        acc0 = __builtin_amdgcn_mfma_f32_16x16x32_bf16(h2, wl[(nt*3+2)*64], acc0, 0, 0, 0);
        int d2 = col - 192;
        int w0 = (VOFF >> 1) + d2*20 + 8*mt + 2*quad;
        sU[w0]     = pk2bf(acc0[0]+acc1[0], acc0[1]+acc1[1]);
        sU[w0 + 1] = pk2bf(acc0[2]+acc1[2], acc0[3]+acc1[3]);
      }
    };
#pragma unroll
    for (int i = 0; i < 4; ++i) qkv_tile(p + 4*i);
    if (p < 2) qkv_tile(p + 16);
  }
  __syncthreads();   // barrier 2

  // ---------- ph2: attention, 24 units (w=0..2 full 16x16 causal; w=3 8x8 causal prefix)
  {
    auto attn_unit = [&](int u){
      int w = u / 6, h = u - 6*(u / 6);
      bool pref = (w == 3);
      short8 qa = {0,0,0,0,0,0,0,0}, ka = {0,0,0,0,0,0,0,0};
      if (quad < 2){
        qa = *(const short8*)(sS +        (8*w + lm)*SH + h*16 + quad*8);
        ka = *(const short8*)(sS + KOFF + (8*w + lm)*SH + h*16 + quad*8);
      }
      f32x4 sc = {0.f,0.f,0.f,0.f};
      sc = __builtin_amdgcn_mfma_f32_16x16x32_bf16(ka, qa, sc, 0, 0, 0);
      float p4[4]; float sum = 0.f;
#pragma unroll
      for (int r = 0; r < 4; ++r){
        int k = quad*4 + r;
        float e = fast_ex2(sc[r]*0.36067376f);   // exp(s/4) = exp2(s/4*log2e)
        bool ok = (k <= lm) && (!pref || (k < 8 && lm < 8));
        p4[r] = ok ? e : 0.f;
        sum += p4[r];
      }
      sum += __shfl_xor(sum, 16);
      sum += __shfl_xor(sum, 32);
      float rs = fast_rcp(sum + 1e-30f);
      int x0 = (int)pk2bf(p4[0]*rs, p4[1]*rs);
      int x1 = (int)pk2bf(p4[2]*rs, p4[3]*rs);
      int srcA = lm + ((quad & 1) << 5);
      int e0 = __shfl(x0, srcA),      e1 = __shfl(x1, srcA);
      int e2 = __shfl(x0, srcA + 16), e3 = __shfl(x1, srcA + 16);
      short8 pa = {0,0,0,0,0,0,0,0}, va = {0,0,0,0,0,0,0,0};
      if (quad < 2){
        u32x4 t = {(unsigned)e0, (unsigned)e1, (unsigned)e2, (unsigned)e3};
        pa = __builtin_bit_cast(short8, t);
        if (!(pref && quad == 1))   // prefix: vT cols 32..39 are pad garbage (and P=0 there)
          va = *(const short8*)(sS + VOFF + (h*16 + lm)*40 + 8*w + quad*8);
      }
      f32x4 oc = {0.f,0.f,0.f,0.f};
      oc = __builtin_amdgcn_mfma_f32_16x16x32_bf16(va, pa, oc, 0, 0, 0); // O^T[d][q]
      unsigned ob = OB_U + (w*16 + lm)*SU + h*8 + quad*2;  // w=3,lm>=8 -> spare region, harmless
      sU[ob]     = pk2bf(oc[0], oc[1]);
      sU[ob + 1] = pk2bf(oc[2], oc[3]);
    };
    attn_unit(wave);
    attn_unit(wave + 8);
    attn_unit(wave + 16);
  }
  __syncthreads();   // barrier 3

  // ---------- ph3: out-proj + residual, 24 tiles (4 w x 6 nt) -> hres[56] @ 0
  {
    auto oproj_tile = [&](int tile){
      int w = tile / 6, nt = tile - 6*(tile / 6);
      f32x4 acc0 = *(const f32x4*)(out_b + nt*16 + quad*4);
      f32x4 acc1 = {0.f,0.f,0.f,0.f};
      const unsigned short* arow = sS + OB_S + (w*16 + lm)*SH + quad*8;
      short8 a0 = *(const short8*)(arow);
      short8 a1 = *(const short8*)(arow + 32);
      short8 a2 = *(const short8*)(arow + 64);
      acc0 = __builtin_amdgcn_mfma_f32_16x16x32_bf16(wl[(54 + nt*3 + 0)*64], a0, acc0, 0, 0, 0);
      acc1 = __builtin_amdgcn_mfma_f32_16x16x32_bf16(wl[(54 + nt*3 + 1)*64], a1, acc1, 0, 0, 0);
      acc0 = __builtin_amdgcn_mfma_f32_16x16x32_bf16(wl[(54 + nt*3 + 2)*64], a2, acc0, 0, 0, 0);
      int xrow = (w < 3) ? (8*w + lm) : min(24 + lm, 31);   // clamp: lm>=8 rows discarded
      f32x4 xr = *(const f32x4*)(x + xbase + (size_t)xrow*96 + nt*16 + quad*4);
      unsigned idx = (w*16 + lm)*SU + nt*8 + quad*2;        // w=3,lm>=8 -> f1p region, pre-ph4: harmless
      sU[idx]     = pk2bf(acc0[0]+acc1[0]+xr[0], acc0[1]+acc1[1]+xr[1]);
      sU[idx + 1] = pk2bf(acc0[2]+acc1[2]+xr[2], acc0[3]+acc1[3]+xr[3]);
    };
    oproj_tile(wave);
    oproj_tile(wave + 8);
    oproj_tile(wave + 16);
  }
  __syncthreads();   // barrier 4

  // ---------- ph4: fused LN2 + FFN1 + gelu; wave owns (mt=wave>>1, 6 nt) -> f1
  {
    const int mt = wave >> 1, ntb = (wave & 1)*6;
    const unsigned short* hr = sS + (16*mt + lm)*SH + quad*8;   // mt=3,lm>=8: garbage, discarded
    u32x4 c0 = __builtin_bit_cast(u32x4, *(const short8*)(hr));
    u32x4 c1 = __builtin_bit_cast(u32x4, *(const short8*)(hr + 32));
    u32x4 c2 = __builtin_bit_cast(u32x4, *(const short8*)(hr + 64));
    float s = 0.f, q2 = 0.f;
#pragma unroll
    for (int t = 0; t < 4; ++t){
      float a0 = bflo(c0[t]), a1 = bfhi(c0[t]);
      float a2 = bflo(c1[t]), a3 = bfhi(c1[t]);
      float a4 = bflo(c2[t]), a5 = bfhi(c2[t]);
      s  += a0+a1+a2+a3+a4+a5;
      q2 += a0*a0+a1*a1+a2*a2+a3*a3+a4*a4+a5*a5;
    }
    s  += __shfl_xor(s, 16);  q2 += __shfl_xor(q2, 16);
    s  += __shfl_xor(s, 32);  q2 += __shfl_xor(q2, 32);
    float mean = s * (1.f/96.f);
    float rstd = fast_rsq(q2 * (1.f/96.f) - mean*mean + 1e-5f);
    auto mkfrag2 = [&](u32x4 c, int kf)->short8{
      const float* gp = ln2_g + kf*32 + quad*8;
      const float* bp = ln2_b + kf*32 + quad*8;
      f32x4 ga = *(const f32x4*)(gp), gb = *(const f32x4*)(gp + 4);
      f32x4 ba = *(const f32x4*)(bp), bb = *(const f32x4*)(bp + 4);
      u32x4 hu;
      hu[0] = pk2bf((bflo(c[0])-mean)*rstd*ga[0]+ba[0], (bfhi(c[0])-mean)*rstd*ga[1]+ba[1]);
      hu[1] = pk2bf((bflo(c[1])-mean)*rstd*ga[2]+ba[2], (bfhi(c[1])-mean)*rstd*ga[3]+ba[3]);
      hu[2] = pk2bf((bflo(c[2])-mean)*rstd*gb[0]+bb[0], (bfhi(c[2])-mean)*rstd*gb[1]+bb[1]);
      hu[3] = pk2bf((bflo(c[3])-mean)*rstd*gb[2]+bb[2], (bfhi(c[3])-mean)*rstd*gb[3]+bb[3]);
      return __builtin_bit_cast(short8, hu);
    };
    short8 a0f = mkfrag2(c0, 0);
    short8 a1f = mkfrag2(c1, 1);
    short8 a2f = mkfrag2(c2, 2);
    unsigned fbase = (mt < 3) ? (unsigned)(F1M_U + (mt*16 + lm)*F1SU)
                              : (unsigned)(F1P_U + lm*F1SU);     // lm>=8 spillover: unread区, safe
#pragma unroll
    for (int i = 0; i < 6; ++i){
      int nt = ntb + i;
      f32x4 acc0 = *(const f32x4*)(ffn_b1 + nt*16 + quad*4);
      f32x4 acc1 = {0.f,0.f,0.f,0.f};
      acc0 = __builtin_amdgcn_mfma_f32_16x16x32_bf16(wl[(72 + nt*3 + 0)*64], a0f, acc0, 0, 0, 0);
      acc1 = __builtin_amdgcn_mfma_f32_16x16x32_bf16(wl[(72 + nt*3 + 1)*64], a1f, acc1, 0, 0, 0);
      acc0 = __builtin_amdgcn_mfma_f32_16x16x32_bf16(wl[(72 + nt*3 + 2)*64], a2f, acc0, 0, 0, 0);
      float gl[4];
#pragma unroll
      for (int r = 0; r < 4; ++r){
        float uu = acc0[r] + acc1[r];
        float z = -2.3022081f * (uu + 0.044715f * uu*uu*uu);   // -(2z)*log2e
        float e = fast_ex2(z);
        gl[r] = uu * fast_rcp(1.f + e);          // u * sigmoid(2z)
      }
      unsigned idx = fbase + nt*8 + quad*2;
      sU[idx]     = pk2bf(gl[0], gl[1]);
      sU[idx + 1] = pk2bf(gl[2], gl[3]);
    }
  }
  __syncthreads();   // barrier 5

  // ---------- ph5: FFN2 + residual, 24 tiles; wave owns (mt=wave>>1, 3 nt); hres RMW
  {
    const int mt = wave >> 1, ntb = (wave & 1)*3;
    const unsigned short* frow = (mt < 3) ? (sS + F1M_S + (mt*16 + lm)*F1S + quad*8)
                                          : (sS + F1P_S + lm*F1S + quad*8);
    const bool wr = (mt < 3) | (lm < 8);   // mt=3,lm>=8 would corrupt f1p region
#pragma unroll
    for (int i = 0; i < 3; ++i){
      int nt = ntb + i;
      short8 f0 = *(const short8*)(frow);
      short8 f1 = *(const short8*)(frow + 32);
      short8 f2 = *(const short8*)(frow + 64);
      short8 f3 = *(const short8*)(frow + 96);
      short8 f4 = *(const short8*)(frow + 128);
      short8 f5 = *(const short8*)(frow + 160);
      f32x4 acc0 = *(const f32x4*)(ffn_b2 + nt*16 + quad*4);
      f32x4 acc1 = {0.f,0.f,0.f,0.f};
      acc0 = __builtin_amdgcn_mfma_f32_16x16x32_bf16(wl[(108 + nt*6 + 0)*64], f0, acc0, 0, 0, 0);
      acc1 = __builtin_amdgcn_mfma_f32_16x16x32_bf16(wl[(108 + nt*6 + 1)*64], f1, acc1, 0, 0, 0);
      acc0 = __builtin_amdgcn_mfma_f32_16x16x32_bf16(wl[(108 + nt*6 + 2)*64], f2, acc0, 0, 0, 0);
      acc1 = __builtin_amdgcn_mfma_f32_16x16x32_bf16(wl[(108 + nt*6 + 3)*64], f3, acc1, 0, 0, 0);
      acc0 = __builtin_amdgcn_mfma_f32_16x16x32_bf16(wl[(108 + nt*6 + 4)*64], f4, acc0, 0, 0, 0);
      acc1 = __builtin_amdgcn_mfma_f32_16x16x32_bf16(wl[(108 + nt*6 + 5)*64], f5, acc1, 0, 0, 0);
      if (wr){
        unsigned idx = (16*mt + lm)*SU + nt*8 + quad*2;
        unsigned u0 = sU[idx], u1 = sU[idx + 1];
        sU[idx]     = pk2bf(bflo(u0)+acc0[0]+acc1[0], bfhi(u0)+acc0[1]+acc1[1]);
        sU[idx + 1] = pk2bf(bflo(u1)+acc0[2]+acc1[2], bfhi(u1)+acc0[3]+acc1[3]);
      }
    }
  }
  __syncthreads();   // barrier 6

  // ---------- ph6: final LN + pairwise average + pure stores (exclusive ownership)
  {
    const int i = tid >> 4, c0 = tid & 15;
    int l, rowA, rowB = -1;
    bool active = true;
    if (i < 24){
      l = t0 + 8 + i;
      rowA = 8 + i + 8*(i >> 3);       // win w rows: 8..15 / 24..31 / 40..47
      rowB = rowA + 8;                 // next-window rows: 16.. / 32.. / 48..(prefix)
      if (g == 340 && i >= 16) rowB = -1;   // window 1023 doesn't exist
    } else if (g == 0){
      l = i - 24;  rowA = i - 24;      // tokens 0..7, single window
    } else active = false;

    if (active){
      const size_t obase = ((size_t)b * 8192 + l) * 96;
      float g6[6], b6[6];
#pragma unroll
      for (int e = 0; e < 6; ++e){ g6[e] = pln_g[c0 + 16*e]; b6[e] = pln_b[c0 + 16*e]; }
      float yA[6];
      {
        float v[6];
#pragma unroll
        for (int e = 0; e < 6; ++e) v[e] = bf1(sS[rowA*SH + c0 + 16*e]);
        float s = 0.f, q2 = 0.f;
#pragma unroll
        for (int e = 0; e < 6; ++e){ s += v[e]; q2 += v[e]*v[e]; }
#pragma unroll
        for (int m = 1; m < 16; m <<= 1){ s += __shfl_xor(s, m, 16); q2 += __shfl_xor(q2, m, 16); }
        float mean = s * (1.f/96.f);
        float rstd = fast_rsq(q2 * (1.f/96.f) - mean*mean + 1e-5f);
#pragma unroll
        for (int e = 0; e < 6; ++e) yA[e] = (v[e]-mean)*rstd*g6[e] + b6[e];
      }
      if (rowB >= 0){
        float yB[6];
        {
          float v[6];
#pragma unroll
          for (int e = 0; e < 6; ++e) v[e] = bf1(sS[rowB*SH + c0 + 16*e]);
          float s = 0.f, q2 = 0.f;
#pragma unroll
          for (int e = 0; e < 6; ++e){ s += v[e]; q2 += v[e]*v[e]; }
#pragma unroll
          for (int m = 1; m < 16; m <<= 1){ s += __shfl_xor(s, m, 16); q2 += __shfl_xor(q2, m, 16); }
          float mean = s * (1.f/96.f);
          float rstd = fast_rsq(q2 * (1.f/96.f) - mean*mean + 1e-5f);
#pragma unroll
          for (int e = 0; e < 6; ++e) yB[e] = (v[e]-mean)*rstd*g6[e] + b6[e];
        }
#pragma unroll
        for (int e = 0; e < 6; ++e)
          out[obase + c0 + 16*e] = 0.5f * (yA[e] + yB[e]);
      } else {
#pragma unroll
        for (int e = 0; e < 6; ++e)
          out[obase + c0 + 16*e] = yA[e];
      }
    }
  }
}

extern "C" void kernel_launch(void* const* d_in, const int* in_sizes, int n_in,
                              void* d_out, int out_size, void* d_ws, size_t ws_size,
                              hipStream_t stream) {
  const float* x      = (const float*)d_in[0];
  const float* ln1_g  = (const float*)d_in[1];
  const float* ln1_b  = (const float*)d_in[2];
  const float* qkv_w  = (const float*)d_in[3];
  const float* qkv_b  = (const float*)d_in[4];
  const float* out_w  = (const float*)d_in[5];
  const float* out_b  = (const float*)d_in[6];
  const float* ln2_g  = (const float*)d_in[7];
  const float* ln2_b  = (const float*)d_in[8];
  const float* ffn_w1 = (const float*)d_in[9];
  const float* ffn_b1 = (const float*)d_in[10];
  const float* ffn_w2 = (const float*)d_in[11];
  const float* ffn_b2 = (const float*)d_in[12];
  const float* pln_g  = (const float*)d_in[13];
  const float* pln_b  = (const float*)d_in[14];
  float* out = (float*)d_out;
  short8* wsv = (short8*)d_ws;

  pack_weights<<<144, 64, 0, stream>>>(qkv_w, out_w, ffn_w1, ffn_w2, wsv);
  fused_block<<<dim3(341, 32), 512, 0, stream>>>(
      x, ln1_g, ln1_b, qkv_b, out_b, ln2_g, ln2_b, ffn_b1, ffn_b2,
      pln_g, pln_b, (const short8*)wsv, out);
}